// Round 8
// baseline (180.006 us; speedup 1.0000x reference)
//
#include <hip/hip_runtime.h>

// EncoderBlock on MI355X. Round 22: in-wave ILP. attn: both q-tiles' QK MFMAs
// issued back-to-back before softmax (tile-a MFMA hides under tile-b VALU
// softmax). tail_fused: per-tile prefetch split into 2 half-phases interleaved
// with the two kk-halves of compute. Sync structure/marks identical to r21
// (174.7 µs). B=16 T=1024 C=256 H=8 D=32. 4 launches.

typedef unsigned short u16;
typedef unsigned int u32;
typedef __attribute__((ext_vector_type(8))) short short8v;  // 8 bf16 MFMA A/B frag
typedef __attribute__((ext_vector_type(4))) float float4v;  // MFMA C/D frag

__device__ __forceinline__ float b2f(u16 u) { union { u32 i; float f; } v; v.i = (u32)u << 16; return v.f; }
__device__ __forceinline__ float lo2f(u32 u) { union { u32 i; float f; } v; v.i = u << 16; return v.f; }
__device__ __forceinline__ float hi2f(u32 u) { union { u32 i; float f; } v; v.i = u & 0xffff0000u; return v.f; }
__device__ __forceinline__ u16 f2b(float f) {
    union { float f; u32 i; } v; v.f = f;
    u32 r = v.i + 0x7fffu + ((v.i >> 16) & 1u);  // RTNE
    return (u16)(r >> 16);
}
__device__ __forceinline__ u32 pk2_rtz(float a, float b) {
    return (__float_as_uint(a) >> 16) | (__float_as_uint(b) & 0xffff0000u);
}
__device__ __forceinline__ void async_cp16(const u16* g, u16* l) {
    __builtin_amdgcn_global_load_lds((const __attribute__((address_space(1))) void*)g,
                                     (__attribute__((address_space(3))) void*)l, 16, 0, 0);
}

// ---------------- fused prep (wqkv pack + 3 transposes) + LN1 ---------------
__global__ __launch_bounds__(256) void prep_ln1(const float* __restrict__ wq,
                                                const float* __restrict__ wk,
                                                const float* __restrict__ wv,
                                                const float* __restrict__ wp,
                                                const float* __restrict__ w1,
                                                const float* __restrict__ w2,
                                                const float* __restrict__ x,
                                                const float* __restrict__ g1,
                                                const float* __restrict__ be1,
                                                u16* __restrict__ wqkvT,
                                                u16* __restrict__ wpT,
                                                u16* __restrict__ w1T,
                                                u16* __restrict__ w2T,
                                                u16* __restrict__ hout) {
    __shared__ u16 tile[64][65];
    int bid = blockIdx.x, tid = threadIdx.x;
    if (bid < 768) {
        int i = bid * 256 + tid;
        int n = i >> 8, k = i & 255;
        int which = n >> 8, nn = n & 255;
        const float* w = which == 0 ? wq : (which == 1 ? wk : wv);
        float v = w[((nn >> 5) * 256 + k) * 32 + (nn & 31)];   // w[h][k][d]
        if (which == 0) v *= 0.09016844f;                      // (1/16)*log2(e)
        wqkvT[i] = f2b(v);
    } else if (bid < 912) {
        const float* src; u16* dst; int K, N, t;
        if (bid < 784)      { src = wp; dst = wpT; K = 256;  N = 256;  t = bid - 768; }
        else if (bid < 848) { src = w1; dst = w1T; K = 256;  N = 1024; t = bid - 784; }
        else                { src = w2; dst = w2T; K = 1024; N = 256;  t = bid - 848; }
        int ntn = N >> 6;
        int k0 = (t / ntn) << 6, n0 = (t % ntn) << 6;
        int lane = tid & 63, wrow = tid >> 6;
        #pragma unroll
        for (int r = 0; r < 16; r++) {
            int k = wrow * 16 + r;
            tile[k][lane] = f2b(src[(size_t)(k0 + k) * N + n0 + lane]);
        }
        __syncthreads();
        #pragma unroll
        for (int r = 0; r < 16; r++) {
            int n = wrow * 16 + r;
            dst[(size_t)(n0 + n) * K + k0 + lane] = tile[lane][n];
        }
    } else {
        int row = (bid - 912) * 4 + (tid >> 6);
        int lane = tid & 63;
        float4 xv = *(const float4*)(x + (size_t)row * 256 + lane * 4);
        float v0 = xv.x, v1 = xv.y, v2 = xv.z, v3 = xv.w;
        float s = v0 + v1 + v2 + v3;
        #pragma unroll
        for (int m = 32; m; m >>= 1) s += __shfl_xor(s, m);
        float mu = s * 0.00390625f;
        float d0 = v0 - mu, d1 = v1 - mu, d2 = v2 - mu, d3 = v3 - mu;
        float ss = d0 * d0 + d1 * d1 + d2 * d2 + d3 * d3;
        #pragma unroll
        for (int m = 32; m; m >>= 1) ss += __shfl_xor(ss, m);
        float rs = rsqrtf(ss * 0.00390625f + 1e-5f);
        float4 g = *(const float4*)(g1 + lane * 4);
        float4 b = *(const float4*)(be1 + lane * 4);
        uint2 r;
        r.x = (u32)f2b(d0 * rs * g.x + b.x) | ((u32)f2b(d1 * rs * g.y + b.y) << 16);
        r.y = (u32)f2b(d2 * rs * g.z + b.z) | ((u32)f2b(d3 * rs * g.w + b.w) << 16);
        *(uint2*)(hout + (size_t)row * 256 + lane * 4) = r;
    }
}

// ---------------- 128x128 MFMA GEMM (qkv): counted-vmcnt double buffer ------
template<bool HASBIAS, bool RELU, bool QKV>
__global__ __launch_bounds__(256) void gemm128(const u16* __restrict__ A,
                                               const u16* __restrict__ Bt,
                                               const float* __restrict__ bias,
                                               u16* __restrict__ out,
                                               u16* __restrict__ vout,
                                               int M, int N, int K) {
    __shared__ __align__(16) u16 SH[32768];      // 64KB
    const int tid = threadIdx.x, lane = tid & 63, w = tid >> 6;
    const int m0 = blockIdx.x * 128, n0 = blockIdx.y * 128;
    const int wm = (w & 1) * 64, wn = (w >> 1) * 64;
    const int fm = lane & 15, q = lane >> 4;

    float4v acc[4][4];
    #pragma unroll
    for (int i = 0; i < 4; i++)
        #pragma unroll
        for (int j = 0; j < 4; j++) acc[i][j] = (float4v){0.f, 0.f, 0.f, 0.f};

    const int kset = ((lane & 7) ^ (lane >> 3)) * 8;
    const u16* Ag = A  + (size_t)(m0 + w * 32 + (lane >> 3)) * K + kset;
    const u16* Bg = Bt + (size_t)(n0 + w * 32 + (lane >> 3)) * K + kset;

    auto issueS = [&](int t, int d) {
        u16* Asw = SH + d * 16384 + (w * 32) * 64;
        u16* Bsw = SH + d * 16384 + 8192 + (w * 32) * 64;
        #pragma unroll
        for (int c = 0; c < 4; c++) {
            async_cp16(Ag + (size_t)c * 8 * K + t * 64, Asw + c * 8 * 64);
            async_cp16(Bg + (size_t)c * 8 * K + t * 64, Bsw + c * 8 * 64);
        }
    };
    issueS(0, 0);
    issueS(1, 1);

    const int sw = fm & 7;
    #pragma unroll
    for (int t = 0; t < 4; ++t) {
        if (t == 3) asm volatile("s_waitcnt vmcnt(0)" ::: "memory");
        else        asm volatile("s_waitcnt vmcnt(8)" ::: "memory");
        __builtin_amdgcn_s_barrier();
        const u16* As = SH + (t & 1) * 16384;
        const u16* Bs = As + 8192;
        __builtin_amdgcn_s_setprio(1);
        #pragma unroll
        for (int kk = 0; kk < 64; kk += 32) {
            const int slot = (((kk >> 3) + q) ^ sw) * 8;
            short8v af[4], bf[4];
            #pragma unroll
            for (int mi = 0; mi < 4; mi++)
                af[mi] = *(const short8v*)&As[(wm + mi * 16 + fm) * 64 + slot];
            #pragma unroll
            for (int ni = 0; ni < 4; ni++)
                bf[ni] = *(const short8v*)&Bs[(wn + ni * 16 + fm) * 64 + slot];
            #pragma unroll
            for (int mi = 0; mi < 4; mi++)
                #pragma unroll
                for (int ni = 0; ni < 4; ni++)
                    acc[mi][ni] = __builtin_amdgcn_mfma_f32_16x16x32_bf16(
                        bf[ni], af[mi], acc[mi][ni], 0, 0, 0);
        }
        __builtin_amdgcn_s_setprio(0);
        if (t < 2) {
            __builtin_amdgcn_s_barrier();
            issueS(t + 2, t & 1);
        }
    }

    if (QKV && n0 >= 512) {
        __syncthreads();
        #pragma unroll
        for (int mi = 0; mi < 4; mi++) {
            int ml = wm + mi * 16 + fm;
            #pragma unroll
            for (int ni = 0; ni < 4; ni++) {
                int nl = wn + ni * 16 + q * 4;
                #pragma unroll
                for (int r = 0; r < 4; r++)
                    SH[(nl + r) * 136 + ml] = f2b(acc[mi][ni][r]);
            }
        }
        __syncthreads();
        int r = tid & 127, c = (tid >> 7) << 6;
        int hd = (n0 - 512) + r;
        int b = m0 >> 10, t0 = m0 & 1023;
        u16* dst = vout + (size_t)(b * 256 + hd) * 1024 + t0 + c;
        const u16* srcT = SH + r * 136 + c;
        #pragma unroll
        for (int i = 0; i < 8; i++)
            *(uint4*)(dst + i * 8) = *(const uint4*)(srcT + i * 8);
        return;
    }

    #pragma unroll
    for (int mi = 0; mi < 4; mi++) {
        int row = m0 + wm + mi * 16 + fm;
        #pragma unroll
        for (int ni = 0; ni < 4; ni++) {
            int nb = n0 + wn + ni * 16 + q * 4;
            float v0 = acc[mi][ni][0], v1 = acc[mi][ni][1],
                  v2 = acc[mi][ni][2], v3 = acc[mi][ni][3];
            if (HASBIAS) {
                float4 bv = *(const float4*)&bias[nb];
                v0 += bv.x; v1 += bv.y; v2 += bv.z; v3 += bv.w;
            }
            if (RELU) {
                v0 = fmaxf(v0, 0.f); v1 = fmaxf(v1, 0.f);
                v2 = fmaxf(v2, 0.f); v3 = fmaxf(v3, 0.f);
            }
            size_t idx = (size_t)row * N + nb;
            uint2 ov;
            ov.x = (u32)f2b(v0) | ((u32)f2b(v1) << 16);
            ov.y = (u32)f2b(v2) | ((u32)f2b(v3) << 16);
            *(uint2*)&out[idx] = ov;
        }
    }
}

// ---------------- tail_fused: proj + LN2 + FFN, one kernel ------------------
// Per tile: issue half1 of B(t+2) -> 8 MFMA (kk=0) -> issue half2 -> 8 MFMA
// (kk=32). vmcnt counts and barriers identical to r21.
#define TMM_A(KH, AFRAG, ACC)                                                     \
    do {                                                                          \
        const int slot_ = ((((KH) ? 4 : 0) + q) ^ sw) * 8;                        \
        short8v bf_[4];                                                           \
        _Pragma("unroll")                                                         \
        for (int ni = 0; ni < 4; ni++)                                            \
            bf_[ni] = *(const short8v*)&Bb[(wn + ni * 16 + fm) * 64 + slot_];     \
        _Pragma("unroll")                                                         \
        for (int mi = 0; mi < 2; mi++)                                            \
            _Pragma("unroll")                                                     \
            for (int ni = 0; ni < 4; ni++)                                        \
                ACC[mi][ni] = __builtin_amdgcn_mfma_f32_16x16x32_bf16(            \
                    bf_[ni], (AFRAG), ACC[mi][ni], 0, 0, 0);                      \
    } while (0)

#define TMM_M(KH, ABASE, ACC)                                                     \
    do {                                                                          \
        const int slot_ = ((((KH) ? 4 : 0) + q) ^ sw) * 8;                        \
        short8v af_[2], bf_[4];                                                   \
        _Pragma("unroll")                                                         \
        for (int mi = 0; mi < 2; mi++)                                            \
            af_[mi] = *(const short8v*)&(ABASE)[(wm + mi * 16 + fm) * 64 + slot_];\
        _Pragma("unroll")                                                         \
        for (int ni = 0; ni < 4; ni++)                                            \
            bf_[ni] = *(const short8v*)&Bb[(wn + ni * 16 + fm) * 64 + slot_];     \
        _Pragma("unroll")                                                         \
        for (int mi = 0; mi < 2; mi++)                                            \
            _Pragma("unroll")                                                     \
            for (int ni = 0; ni < 4; ni++)                                        \
                ACC[mi][ni] = __builtin_amdgcn_mfma_f32_16x16x32_bf16(            \
                    bf_[ni], af_[mi], ACC[mi][ni], 0, 0, 0);                      \
    } while (0)

__global__ __launch_bounds__(512, 1) void tail_fused(const u16* __restrict__ att,
                                                     const u16* __restrict__ wpT,
                                                     const float* __restrict__ bp,
                                                     const float* __restrict__ x,
                                                     const float* __restrict__ g2,
                                                     const float* __restrict__ be2,
                                                     const u16* __restrict__ w1T,
                                                     const float* __restrict__ b1,
                                                     const u16* __restrict__ w2T,
                                                     const float* __restrict__ b2,
                                                     float* __restrict__ out) {
    __shared__ __align__(16) u16 SH[65536];   // 128KB: Ms/Hs 32K | Bs 3x32K
    __shared__ float ps[2][2][16][4], pq[2][2][16][4];
    u16* Ms = SH;             // [4 kc][64][64]: h2 (interlude) then mid chunks
    u16* Bs = SH + 16384;     // 3 x [256][64] weight tile (triple buffer)
    const int tid = threadIdx.x, lane = tid & 63, w = tid >> 6;
    const int m0 = blockIdx.x * 64;
    const int wmi = w & 1, wni = w >> 1;
    const int wm = wmi * 32;                  // m-half (32 rows)
    const int wn = wni * 64;                  // n-quarter (64 cols)
    const int fm = lane & 15, q = lane >> 4;
    const int sw = fm & 7;
    const int kset = ((lane & 7) ^ (lane >> 3)) * 8;
    const int rb = w * 8 + (lane >> 3);       // staging row 0..63

    // ---- A-frags (att) into registers: ar[kcn][mi] = att[row][kcn*32+q*8] --
    short8v ar[8][2];
    {
        const u16* Abase = att + (size_t)(m0 + wm + fm) * 256 + q * 8;
        #pragma unroll
        for (int kcn = 0; kcn < 8; kcn++)
            #pragma unroll
            for (int mi = 0; mi < 2; mi++)
                ar[kcn][mi] = *(const short8v*)(Abase + (size_t)mi * 16 * 256 + kcn * 32);
    }

    // ---- B-tile half-issue: h=0 -> c{0,1}, h=1 -> c{2,3} ----
    auto issueBh = [&](int u, u16* dst, int h) {
        const int c0 = h * 2;
        if (u < 4) {
            const u16* src = wpT + (size_t)rb * 256 + u * 64 + kset;
            #pragma unroll
            for (int c = c0; c < c0 + 2; c++)
                async_cp16(src + (size_t)c * 64 * 256, dst + c * 4096);
        } else {
            const int tt = u - 4, n2 = tt >> 3, k2 = tt & 3;
            if (((tt >> 2) & 1) == 0) {
                const u16* src = w1T + (size_t)(n2 * 256 + rb) * 256 + k2 * 64 + kset;
                #pragma unroll
                for (int c = c0; c < c0 + 2; c++)
                    async_cp16(src + (size_t)c * 64 * 256, dst + c * 4096);
            } else {
                const u16* src = w2T + (size_t)rb * 1024 + n2 * 256 + k2 * 64 + kset;
                #pragma unroll
                for (int c = c0; c < c0 + 2; c++)
                    async_cp16(src + (size_t)c * 64 * 1024, dst + c * 4096);
            }
        }
    };

    issueBh(0, Bs + w * 512, 0); issueBh(0, Bs + w * 512, 1);
    issueBh(1, Bs + 16384 + w * 512, 0); issueBh(1, Bs + 16384 + w * 512, 1);

    float4v acc1[2][4], acc2[2][4], xr[2][4];
    #pragma unroll
    for (int i = 0; i < 2; i++)
        #pragma unroll
        for (int j = 0; j < 4; j++) {
            acc1[i][j] = (float4v){0.f, 0.f, 0.f, 0.f};   // proj accumulator
            acc2[i][j] = (float4v){0.f, 0.f, 0.f, 0.f};
        }

    #pragma unroll
    for (int t = 0; t < 36; ++t) {
        if (t == 35) asm volatile("s_waitcnt vmcnt(0)" ::: "memory");
        else         asm volatile("s_waitcnt vmcnt(4)" ::: "memory");
        __builtin_amdgcn_s_barrier();
        u16* dstB = Bs + ((t + 2) % 3) * 16384 + w * 512;
        const bool doIss = (t + 2 < 36);
        if (doIss) issueBh(t + 2, dstB, 0);
        const u16* Bb = Bs + (t % 3) * 16384;

        if (t < 4) {
            // ---- proj tile t: acc1 += att-frag x wpT-tile ----
            __builtin_amdgcn_s_setprio(1);
            TMM_A(0, ar[t * 2 + 0][mi], acc1);
            __builtin_amdgcn_s_setprio(0);
            if (doIss) issueBh(t + 2, dstB, 1);
            __builtin_amdgcn_s_setprio(1);
            TMM_A(1, ar[t * 2 + 1][mi], acc1);
            __builtin_amdgcn_s_setprio(0);
            if (t == 3) {
                // ======== LN2 interlude ========
                float s[2] = {0.f, 0.f}, s2[2] = {0.f, 0.f};
                #pragma unroll
                for (int mi = 0; mi < 2; mi++)
                    #pragma unroll
                    for (int ni = 0; ni < 4; ni++) {
                        const int nb = wn + ni * 16 + q * 4;
                        const int row = m0 + wm + mi * 16 + fm;
                        float4 bv = *(const float4*)&bp[nb];
                        float4 xv = *(const float4*)(x + (size_t)row * 256 + nb);
                        #pragma unroll
                        for (int r = 0; r < 4; r++) {
                            float tv = acc1[mi][ni][r] + (&bv.x)[r] + (&xv.x)[r];
                            xr[mi][ni][r] = tv;
                            s[mi] += tv; s2[mi] += tv * tv;
                        }
                    }
                #pragma unroll
                for (int mi = 0; mi < 2; mi++) {
                    s[mi]  += __shfl_xor(s[mi], 16);  s[mi]  += __shfl_xor(s[mi], 32);
                    s2[mi] += __shfl_xor(s2[mi], 16); s2[mi] += __shfl_xor(s2[mi], 32);
                }
                if (q == 0) {
                    ps[wmi][0][fm][wni] = s[0];  ps[wmi][1][fm][wni] = s[1];
                    pq[wmi][0][fm][wni] = s2[0]; pq[wmi][1][fm][wni] = s2[1];
                }
                asm volatile("s_waitcnt lgkmcnt(0)" ::: "memory");
                __builtin_amdgcn_s_barrier();
                float mu[2], rs[2];
                #pragma unroll
                for (int mi = 0; mi < 2; mi++) {
                    float S  = ps[wmi][mi][fm][0] + ps[wmi][mi][fm][1]
                             + ps[wmi][mi][fm][2] + ps[wmi][mi][fm][3];
                    float SQ = pq[wmi][mi][fm][0] + pq[wmi][mi][fm][1]
                             + pq[wmi][mi][fm][2] + pq[wmi][mi][fm][3];
                    mu[mi] = S * 0.00390625f;
                    rs[mi] = rsqrtf(SQ * 0.00390625f - mu[mi] * mu[mi] + 1e-5f);
                }
                // h2 -> Ms (Hs) in swizzled A layout
                #pragma unroll
                for (int ni = 0; ni < 4; ni++) {
                    const int c2 = wn + ni * 16 + q * 4;
                    const int kcM = c2 >> 6, cc = c2 & 63;
                    float4 gv = *(const float4*)&g2[c2];
                    float4 bv = *(const float4*)&be2[c2];
                    #pragma unroll
                    for (int mi = 0; mi < 2; mi++) {
                        const int row = wm + mi * 16 + fm;
                        float h0 = (xr[mi][ni][0] - mu[mi]) * rs[mi] * gv.x + bv.x;
                        float h1 = (xr[mi][ni][1] - mu[mi]) * rs[mi] * gv.y + bv.y;
                        float h2v = (xr[mi][ni][2] - mu[mi]) * rs[mi] * gv.z + bv.z;
                        float h3 = (xr[mi][ni][3] - mu[mi]) * rs[mi] * gv.w + bv.w;
                        uint2 pp;
                        pp.x = (u32)f2b(h0) | ((u32)f2b(h1) << 16);
                        pp.y = (u32)f2b(h2v) | ((u32)f2b(h3) << 16);
                        *(uint2*)&Ms[kcM * 4096 + row * 64 +
                                     (((cc >> 3) ^ (row & 7)) * 8) + (cc & 7)] = pp;
                    }
                }
                asm volatile("s_waitcnt lgkmcnt(0)" ::: "memory");
                __builtin_amdgcn_s_barrier();
                // reload ar from Ms(Hs): ar[kcn][mi] = h2[row][kcn*32 + q*8]
                #pragma unroll
                for (int kcn = 0; kcn < 8; kcn++) {
                    const int kcq = kcn >> 1, kk = (kcn & 1) * 32;
                    const int slot = (((kk >> 3) + q) ^ sw) * 8;
                    #pragma unroll
                    for (int mi = 0; mi < 2; mi++)
                        ar[kcn][mi] = *(const short8v*)&Ms[kcq * 4096 +
                                        (wm + mi * 16 + fm) * 64 + slot];
                }
            }
        } else {
            const int tt = t - 4;
            const int nch = tt >> 3, ph = (tt >> 2) & 1, kc = tt & 3;
            if (ph == 0) {
                if (kc == 0) {
                    #pragma unroll
                    for (int i = 0; i < 2; i++)
                        #pragma unroll
                        for (int j = 0; j < 4; j++) acc1[i][j] = (float4v){0.f, 0.f, 0.f, 0.f};
                }
                __builtin_amdgcn_s_setprio(1);
                TMM_A(0, ar[kc * 2 + 0][mi], acc1);
                __builtin_amdgcn_s_setprio(0);
                if (doIss) issueBh(t + 2, dstB, 1);
                __builtin_amdgcn_s_setprio(1);
                TMM_A(1, ar[kc * 2 + 1][mi], acc1);
                __builtin_amdgcn_s_setprio(0);
                if (kc == 3) {
                    // bias + relu -> Ms (swizzled A layout for gemm2)
                    #pragma unroll
                    for (int ni = 0; ni < 4; ni++) {
                        const int c2 = wn + ni * 16 + q * 4;       // 0..255
                        const int kcM = c2 >> 6, cc = c2 & 63;
                        float4 bv = *(const float4*)&b1[nch * 256 + c2];
                        #pragma unroll
                        for (int mi = 0; mi < 2; mi++) {
                            const int row = wm + mi * 16 + fm;
                            float v0 = fmaxf(acc1[mi][ni][0] + bv.x, 0.f);
                            float v1 = fmaxf(acc1[mi][ni][1] + bv.y, 0.f);
                            float v2 = fmaxf(acc1[mi][ni][2] + bv.z, 0.f);
                            float v3 = fmaxf(acc1[mi][ni][3] + bv.w, 0.f);
                            uint2 pp;
                            pp.x = (u32)f2b(v0) | ((u32)f2b(v1) << 16);
                            pp.y = (u32)f2b(v2) | ((u32)f2b(v3) << 16);
                            *(uint2*)&Ms[kcM * 4096 + row * 64 +
                                         (((cc >> 3) ^ (row & 7)) * 8) + (cc & 7)] = pp;
                        }
                    }
                    asm volatile("s_waitcnt lgkmcnt(0)" ::: "memory");
                }
            } else {
                const u16* Ab = Ms + kc * 4096;
                __builtin_amdgcn_s_setprio(1);
                TMM_M(0, Ab, acc2);
                __builtin_amdgcn_s_setprio(0);
                if (doIss) issueBh(t + 2, dstB, 1);
                __builtin_amdgcn_s_setprio(1);
                TMM_M(1, Ab, acc2);
                __builtin_amdgcn_s_setprio(0);
            }
        }
    }

    // ---- epilogue: out = xr (= x + att@wp + bp) + acc2 + b2, fp32 stores ---
    #pragma unroll
    for (int mi = 0; mi < 2; mi++) {
        const int row = m0 + wm + mi * 16 + fm;
        #pragma unroll
        for (int ni = 0; ni < 4; ni++) {
            const int nb = wn + ni * 16 + q * 4;
            size_t idx = (size_t)row * 256 + nb;
            float4 bv = *(const float4*)&b2[nb];
            float v0 = acc2[mi][ni][0] + bv.x + xr[mi][ni][0];
            float v1 = acc2[mi][ni][1] + bv.y + xr[mi][ni][1];
            float v2 = acc2[mi][ni][2] + bv.z + xr[mi][ni][2];
            float v3 = acc2[mi][ni][3] + bv.w + xr[mi][ni][3];
            *(float4*)&out[idx] = (float4){v0, v1, v2, v3};
        }
    }
}

// ---------------- MFMA flash attention: dbuf K/V, paired QK MFMAs -----------
#define SM_PV(S0_, S1_, S2_, S3_, TQ, WQ0, LSUM, O0, O1)                          \
    do {                                                                          \
        float p[16];                                                              \
        _Pragma("unroll")                                                         \
        for (int r = 0; r < 4; r++) {                                             \
            p[r] = exp2f((S0_)[r]);      p[4 + r] = exp2f((S1_)[r]);              \
            p[8 + r] = exp2f((S2_)[r]);  p[12 + r] = exp2f((S3_)[r]);             \
        }                                                                         \
        if (s0 + 63 > (WQ0)) {                                                    \
            int sb_ = s0 + q * 4;                                                 \
            _Pragma("unroll")                                                     \
            for (int c = 0; c < 4; c++)                                           \
                _Pragma("unroll")                                                 \
                for (int r = 0; r < 4; r++)                                       \
                    if (sb_ + c * 16 + r > (TQ)) p[c * 4 + r] = 0.f;              \
        }                                                                         \
        float rsum = 0.f;                                                         \
        _Pragma("unroll")                                                         \
        for (int i = 0; i < 16; i++) rsum += p[i];                                \
        rsum += __shfl_xor(rsum, 16);                                             \
        rsum += __shfl_xor(rsum, 32);                                             \
        LSUM += rsum;                                                             \
        _Pragma("unroll")                                                         \
        for (int c = 0; c < 4; c++) {                                             \
            uint2 pp;                                                             \
            pp.x = pk2_rtz(p[c * 4 + 0], p[c * 4 + 1]);                           \
            pp.y = pk2_rtz(p[c * 4 + 2], p[c * 4 + 3]);                           \
            *(uint2*)&Pl[w][fm][c * 16 + q * 4] = pp;                             \
        }                                                                         \
        short8v pf0 = *(const short8v*)&Pl[w][fm][q * 8];                         \
        short8v pf1 = *(const short8v*)&Pl[w][fm][32 + q * 8];                    \
        __builtin_amdgcn_s_setprio(1);                                            \
        O0 = __builtin_amdgcn_mfma_f32_16x16x32_bf16(vf00, pf0, O0, 0, 0, 0);     \
        O0 = __builtin_amdgcn_mfma_f32_16x16x32_bf16(vf01, pf1, O0, 0, 0, 0);     \
        O1 = __builtin_amdgcn_mfma_f32_16x16x32_bf16(vf10, pf0, O1, 0, 0, 0);     \
        O1 = __builtin_amdgcn_mfma_f32_16x16x32_bf16(vf11, pf1, O1, 0, 0, 0);     \
        __builtin_amdgcn_s_setprio(0);                                            \
    } while (0)

__global__ __launch_bounds__(256) void attn_mfma(const u16* __restrict__ qk,
                                                 const u16* __restrict__ vtg,
                                                 u16* __restrict__ att) {
    const int T = 1024;
    int jj = (blockIdx.x + (blockIdx.y >> 3)) & 7;
    int b = blockIdx.y >> 3, hh = blockIdx.y & 7;
    int tid = threadIdx.x;
    int lane = tid & 63, w = tid >> 6;
    int fm = lane & 15, q = lane >> 4;

    __shared__ __align__(16) u16 Ks[2][64][72];
    __shared__ __align__(16) u16 Vt[2][32][72];
    __shared__ __align__(16) u16 Pl[4][16][72];

    size_t base = (size_t)b * T * 512;
    const u16* kb = qk + base + 256 + hh * 32;
    const u16* vt = vtg + (size_t)((b * 8 + hh) * 32) * 1024;
    const int krow = tid >> 2, kcol = (tid & 3) * 8;
    const int vd = tid >> 3, vs = (tid & 7) * 8;

    int qa0 = jj * 64, qb0 = (15 - jj) * 64;
    int tqa = qa0 + w * 16 + fm, tqb = qb0 + w * 16 + fm;
    short8v qfa = *(const short8v*)(qk + base + (size_t)tqa * 512 + hh * 32 + q * 8);
    short8v qfb = *(const short8v*)(qk + base + (size_t)tqb * 512 + hh * 32 + q * 8);
    float4v oa0 = {0.f, 0.f, 0.f, 0.f}, oa1 = {0.f, 0.f, 0.f, 0.f};
    float4v ob0 = {0.f, 0.f, 0.f, 0.f}, ob1 = {0.f, 0.f, 0.f, 0.f};
    float la = 0.f, lb = 0.f;
    int wqa = qa0 + w * 16, wqb = qb0 + w * 16;
    int nIter = 16 - jj;

    uint4 kreg = *(const uint4*)(kb + (size_t)krow * 512 + kcol);
    uint4 vreg = *(const uint4*)(vt + (size_t)vd * 1024 + vs);

    for (int it = 0; it < nIter; ++it) {
        int s0 = it << 6;
        const int cb = it & 1;
        *(uint4*)&Ks[cb][krow][kcol] = kreg;
        *(uint4*)&Vt[cb][vd][vs] = vreg;
        if (it + 1 < nIter) {
            int ns0 = s0 + 64;
            kreg = *(const uint4*)(kb + (size_t)(ns0 + krow) * 512 + kcol);
            vreg = *(const uint4*)(vt + (size_t)vd * 1024 + ns0 + vs);
        }
        asm volatile("s_waitcnt lgkmcnt(0)" ::: "memory");
        __builtin_amdgcn_s_barrier();
        short8v kf0 = *(const short8v*)&Ks[cb][fm][q * 8];
        short8v kf1 = *(const short8v*)&Ks[cb][16 + fm][q * 8];
        short8v kf2 = *(const short8v*)&Ks[cb][32 + fm][q * 8];
        short8v kf3 = *(const short8v*)&Ks[cb][48 + fm][q * 8];
        short8v vf00 = *(const short8v*)&Vt[cb][fm][q * 8];
        short8v vf01 = *(const short8v*)&Vt[cb][fm][32 + q * 8];
        short8v vf10 = *(const short8v*)&Vt[cb][16 + fm][q * 8];
        short8v vf11 = *(const short8v*)&Vt[cb][16 + fm][32 + q * 8];
        float4v z = {0.f, 0.f, 0.f, 0.f};
        const bool actA = (s0 < wqa + 16);   // wave-uniform; tile b always active

        // ---- paired QK: both q-tiles' MFMAs issue before any softmax ----
        __builtin_amdgcn_s_setprio(1);
        float4v sb0 = __builtin_amdgcn_mfma_f32_16x16x32_bf16(kf0, qfb, z, 0, 0, 0);
        float4v sb1 = __builtin_amdgcn_mfma_f32_16x16x32_bf16(kf1, qfb, z, 0, 0, 0);
        float4v sb2 = __builtin_amdgcn_mfma_f32_16x16x32_bf16(kf2, qfb, z, 0, 0, 0);
        float4v sb3 = __builtin_amdgcn_mfma_f32_16x16x32_bf16(kf3, qfb, z, 0, 0, 0);
        float4v sa0 = z, sa1 = z, sa2 = z, sa3 = z;
        if (actA) {
            sa0 = __builtin_amdgcn_mfma_f32_16x16x32_bf16(kf0, qfa, z, 0, 0, 0);
            sa1 = __builtin_amdgcn_mfma_f32_16x16x32_bf16(kf1, qfa, z, 0, 0, 0);
            sa2 = __builtin_amdgcn_mfma_f32_16x16x32_bf16(kf2, qfa, z, 0, 0, 0);
            sa3 = __builtin_amdgcn_mfma_f32_16x16x32_bf16(kf3, qfa, z, 0, 0, 0);
        }
        __builtin_amdgcn_s_setprio(0);

        SM_PV(sb0, sb1, sb2, sb3, tqb, wqb, lb, ob0, ob1);
        if (actA) SM_PV(sa0, sa1, sa2, sa3, tqa, wqa, la, oa0, oa1);
    }

    #pragma unroll
    for (int t2 = 0; t2 < 2; t2++) {
        float inv = 1.f / (t2 ? la : lb);
        float4v o0 = t2 ? oa0 : ob0, o1 = t2 ? oa1 : ob1;
        int tq = t2 ? tqa : tqb;
        uint2 r0, r1;
        r0.x = (u32)f2b(o0[0] * inv) | ((u32)f2b(o0[1] * inv) << 16);
        r0.y = (u32)f2b(o0[2] * inv) | ((u32)f2b(o0[3] * inv) << 16);
        r1.x = (u32)f2b(o1[0] * inv) | ((u32)f2b(o1[1] * inv) << 16);
        r1.y = (u32)f2b(o1[2] * inv) | ((u32)f2b(o1[3] * inv) << 16);
        size_t o = (size_t)(b * T + tq) * 256 + hh * 32;
        *(uint2*)(att + o + q * 4) = r0;
        *(uint2*)(att + o + 16 + q * 4) = r1;
    }
}

// ---------------- launch ----------------
extern "C" void kernel_launch(void* const* d_in, const int* in_sizes, int n_in,
                              void* d_out, int out_size, void* d_ws, size_t ws_size,
                              hipStream_t stream) {
    const int BT = 16 * 1024;
    const float* x      = (const float*)d_in[0];
    const float* wq     = (const float*)d_in[1];
    const float* wk     = (const float*)d_in[2];
    const float* wv     = (const float*)d_in[3];
    const float* w_proj = (const float*)d_in[4];
    const float* b_proj = (const float*)d_in[5];
    const float* w1     = (const float*)d_in[6];
    const float* b1     = (const float*)d_in[7];
    const float* w2     = (const float*)d_in[8];
    const float* b2     = (const float*)d_in[9];
    const float* ln1_g  = (const float*)d_in[10];
    const float* ln1_b  = (const float*)d_in[11];
    const float* ln2_g  = (const float*)d_in[12];
    const float* ln2_b  = (const float*)d_in[13];

    // Workspace: [8M,16M) hbuf h->att | [16M,32M) qk | [32M,48M) vtg
    //            [48M...) packed weights (1.5M)
    char* ws = (char*)d_ws;
    const size_t MB = 1024 * 1024;
    u16*  hbuf  = (u16*)(ws + 8 * MB);
    u16*  qk    = (u16*)(ws + 16 * MB);
    u16*  vtg   = (u16*)(ws + 32 * MB);
    u16*  wqkvT = (u16*)(ws + 48 * MB);
    u16*  wpT   = (u16*)(ws + 48 * MB + 0x60000);
    u16*  w1T   = (u16*)(ws + 48 * MB + 0x80000);
    u16*  w2T   = (u16*)(ws + 48 * MB + 0x100000);

    prep_ln1<<<5008, 256, 0, stream>>>(wq, wk, wv, w_proj, w1, w2, x, ln1_g, ln1_b,
                                       wqkvT, wpT, w1T, w2T, hbuf);
    // qk | vtg = h @ [Wq'|Wk|Wv]  [counted-vmcnt dbuf]
    gemm128<false, false, true><<<dim3(128, 6), 256, 0, stream>>>(
        hbuf, wqkvT, nullptr, qk, vtg, BT, 512, 256);
    // att = flash attention (writes over h)  [dbuf K/V, paired QK]
    attn_mfma<<<dim3(8, 128), 256, 0, stream>>>(qk, vtg, hbuf);
    // out = x2 + relu(LN2(x + att@wp + bp) @ w1 + b1) @ w2 + b2  [one kernel]
    tail_fused<<<256, 512, 0, stream>>>(hbuf, wpT, b_proj, x, ln2_g, ln2_b,
                                        w1T, b1, w2T, b2, (float*)d_out);
}

// Round 9
// 173.802 us; speedup vs baseline: 1.0357x; 1.0357x over previous
//
#include <hip/hip_runtime.h>

// EncoderBlock on MI355X. Round 23: REVERT to r21 (best verified, 174.7 µs).
// r22's two ILP edits (paired-QK regs in attn, half-issue interleave in tail)
// both regressed (+5.3 µs) — VGPR-pressure occupancy cliff + defeating the
// compiler scheduler. This is r21 verbatim: attn dbuf K/V (1 barrier/tile) +
// setprio on MFMA clusters; counted-vmcnt everywhere; tail_fused one-kernel
// proj+LN2+FFN. B=16 T=1024 C=256 H=8 D=32. 4 launches.

typedef unsigned short u16;
typedef unsigned int u32;
typedef __attribute__((ext_vector_type(8))) short short8v;  // 8 bf16 MFMA A/B frag
typedef __attribute__((ext_vector_type(4))) float float4v;  // MFMA C/D frag

__device__ __forceinline__ float b2f(u16 u) { union { u32 i; float f; } v; v.i = (u32)u << 16; return v.f; }
__device__ __forceinline__ float lo2f(u32 u) { union { u32 i; float f; } v; v.i = u << 16; return v.f; }
__device__ __forceinline__ float hi2f(u32 u) { union { u32 i; float f; } v; v.i = u & 0xffff0000u; return v.f; }
__device__ __forceinline__ u16 f2b(float f) {
    union { float f; u32 i; } v; v.f = f;
    u32 r = v.i + 0x7fffu + ((v.i >> 16) & 1u);  // RTNE
    return (u16)(r >> 16);
}
__device__ __forceinline__ u32 pk2_rtz(float a, float b) {
    return (__float_as_uint(a) >> 16) | (__float_as_uint(b) & 0xffff0000u);
}
__device__ __forceinline__ void async_cp16(const u16* g, u16* l) {
    __builtin_amdgcn_global_load_lds((const __attribute__((address_space(1))) void*)g,
                                     (__attribute__((address_space(3))) void*)l, 16, 0, 0);
}

// ---------------- fused prep (wqkv pack + 3 transposes) + LN1 ---------------
__global__ __launch_bounds__(256) void prep_ln1(const float* __restrict__ wq,
                                                const float* __restrict__ wk,
                                                const float* __restrict__ wv,
                                                const float* __restrict__ wp,
                                                const float* __restrict__ w1,
                                                const float* __restrict__ w2,
                                                const float* __restrict__ x,
                                                const float* __restrict__ g1,
                                                const float* __restrict__ be1,
                                                u16* __restrict__ wqkvT,
                                                u16* __restrict__ wpT,
                                                u16* __restrict__ w1T,
                                                u16* __restrict__ w2T,
                                                u16* __restrict__ hout) {
    __shared__ u16 tile[64][65];
    int bid = blockIdx.x, tid = threadIdx.x;
    if (bid < 768) {
        int i = bid * 256 + tid;
        int n = i >> 8, k = i & 255;
        int which = n >> 8, nn = n & 255;
        const float* w = which == 0 ? wq : (which == 1 ? wk : wv);
        float v = w[((nn >> 5) * 256 + k) * 32 + (nn & 31)];   // w[h][k][d]
        if (which == 0) v *= 0.09016844f;                      // (1/16)*log2(e)
        wqkvT[i] = f2b(v);
    } else if (bid < 912) {
        const float* src; u16* dst; int K, N, t;
        if (bid < 784)      { src = wp; dst = wpT; K = 256;  N = 256;  t = bid - 768; }
        else if (bid < 848) { src = w1; dst = w1T; K = 256;  N = 1024; t = bid - 784; }
        else                { src = w2; dst = w2T; K = 1024; N = 256;  t = bid - 848; }
        int ntn = N >> 6;
        int k0 = (t / ntn) << 6, n0 = (t % ntn) << 6;
        int lane = tid & 63, wrow = tid >> 6;
        #pragma unroll
        for (int r = 0; r < 16; r++) {
            int k = wrow * 16 + r;
            tile[k][lane] = f2b(src[(size_t)(k0 + k) * N + n0 + lane]);
        }
        __syncthreads();
        #pragma unroll
        for (int r = 0; r < 16; r++) {
            int n = wrow * 16 + r;
            dst[(size_t)(n0 + n) * K + k0 + lane] = tile[lane][n];
        }
    } else {
        int row = (bid - 912) * 4 + (tid >> 6);
        int lane = tid & 63;
        float4 xv = *(const float4*)(x + (size_t)row * 256 + lane * 4);
        float v0 = xv.x, v1 = xv.y, v2 = xv.z, v3 = xv.w;
        float s = v0 + v1 + v2 + v3;
        #pragma unroll
        for (int m = 32; m; m >>= 1) s += __shfl_xor(s, m);
        float mu = s * 0.00390625f;
        float d0 = v0 - mu, d1 = v1 - mu, d2 = v2 - mu, d3 = v3 - mu;
        float ss = d0 * d0 + d1 * d1 + d2 * d2 + d3 * d3;
        #pragma unroll
        for (int m = 32; m; m >>= 1) ss += __shfl_xor(ss, m);
        float rs = rsqrtf(ss * 0.00390625f + 1e-5f);
        float4 g = *(const float4*)(g1 + lane * 4);
        float4 b = *(const float4*)(be1 + lane * 4);
        uint2 r;
        r.x = (u32)f2b(d0 * rs * g.x + b.x) | ((u32)f2b(d1 * rs * g.y + b.y) << 16);
        r.y = (u32)f2b(d2 * rs * g.z + b.z) | ((u32)f2b(d3 * rs * g.w + b.w) << 16);
        *(uint2*)(hout + (size_t)row * 256 + lane * 4) = r;
    }
}

// ---------------- 128x128 MFMA GEMM (qkv): counted-vmcnt double buffer ------
template<bool HASBIAS, bool RELU, bool QKV>
__global__ __launch_bounds__(256) void gemm128(const u16* __restrict__ A,
                                               const u16* __restrict__ Bt,
                                               const float* __restrict__ bias,
                                               u16* __restrict__ out,
                                               u16* __restrict__ vout,
                                               int M, int N, int K) {
    __shared__ __align__(16) u16 SH[32768];      // 64KB
    const int tid = threadIdx.x, lane = tid & 63, w = tid >> 6;
    const int m0 = blockIdx.x * 128, n0 = blockIdx.y * 128;
    const int wm = (w & 1) * 64, wn = (w >> 1) * 64;
    const int fm = lane & 15, q = lane >> 4;

    float4v acc[4][4];
    #pragma unroll
    for (int i = 0; i < 4; i++)
        #pragma unroll
        for (int j = 0; j < 4; j++) acc[i][j] = (float4v){0.f, 0.f, 0.f, 0.f};

    const int kset = ((lane & 7) ^ (lane >> 3)) * 8;
    const u16* Ag = A  + (size_t)(m0 + w * 32 + (lane >> 3)) * K + kset;
    const u16* Bg = Bt + (size_t)(n0 + w * 32 + (lane >> 3)) * K + kset;

    auto issueS = [&](int t, int d) {
        u16* Asw = SH + d * 16384 + (w * 32) * 64;
        u16* Bsw = SH + d * 16384 + 8192 + (w * 32) * 64;
        #pragma unroll
        for (int c = 0; c < 4; c++) {
            async_cp16(Ag + (size_t)c * 8 * K + t * 64, Asw + c * 8 * 64);
            async_cp16(Bg + (size_t)c * 8 * K + t * 64, Bsw + c * 8 * 64);
        }
    };
    issueS(0, 0);
    issueS(1, 1);

    const int sw = fm & 7;
    #pragma unroll
    for (int t = 0; t < 4; ++t) {
        if (t == 3) asm volatile("s_waitcnt vmcnt(0)" ::: "memory");
        else        asm volatile("s_waitcnt vmcnt(8)" ::: "memory");
        __builtin_amdgcn_s_barrier();
        const u16* As = SH + (t & 1) * 16384;
        const u16* Bs = As + 8192;
        __builtin_amdgcn_s_setprio(1);
        #pragma unroll
        for (int kk = 0; kk < 64; kk += 32) {
            const int slot = (((kk >> 3) + q) ^ sw) * 8;
            short8v af[4], bf[4];
            #pragma unroll
            for (int mi = 0; mi < 4; mi++)
                af[mi] = *(const short8v*)&As[(wm + mi * 16 + fm) * 64 + slot];
            #pragma unroll
            for (int ni = 0; ni < 4; ni++)
                bf[ni] = *(const short8v*)&Bs[(wn + ni * 16 + fm) * 64 + slot];
            #pragma unroll
            for (int mi = 0; mi < 4; mi++)
                #pragma unroll
                for (int ni = 0; ni < 4; ni++)
                    acc[mi][ni] = __builtin_amdgcn_mfma_f32_16x16x32_bf16(
                        bf[ni], af[mi], acc[mi][ni], 0, 0, 0);
        }
        __builtin_amdgcn_s_setprio(0);
        if (t < 2) {
            __builtin_amdgcn_s_barrier();
            issueS(t + 2, t & 1);
        }
    }

    if (QKV && n0 >= 512) {
        __syncthreads();
        #pragma unroll
        for (int mi = 0; mi < 4; mi++) {
            int ml = wm + mi * 16 + fm;
            #pragma unroll
            for (int ni = 0; ni < 4; ni++) {
                int nl = wn + ni * 16 + q * 4;
                #pragma unroll
                for (int r = 0; r < 4; r++)
                    SH[(nl + r) * 136 + ml] = f2b(acc[mi][ni][r]);
            }
        }
        __syncthreads();
        int r = tid & 127, c = (tid >> 7) << 6;
        int hd = (n0 - 512) + r;
        int b = m0 >> 10, t0 = m0 & 1023;
        u16* dst = vout + (size_t)(b * 256 + hd) * 1024 + t0 + c;
        const u16* srcT = SH + r * 136 + c;
        #pragma unroll
        for (int i = 0; i < 8; i++)
            *(uint4*)(dst + i * 8) = *(const uint4*)(srcT + i * 8);
        return;
    }

    #pragma unroll
    for (int mi = 0; mi < 4; mi++) {
        int row = m0 + wm + mi * 16 + fm;
        #pragma unroll
        for (int ni = 0; ni < 4; ni++) {
            int nb = n0 + wn + ni * 16 + q * 4;
            float v0 = acc[mi][ni][0], v1 = acc[mi][ni][1],
                  v2 = acc[mi][ni][2], v3 = acc[mi][ni][3];
            if (HASBIAS) {
                float4 bv = *(const float4*)&bias[nb];
                v0 += bv.x; v1 += bv.y; v2 += bv.z; v3 += bv.w;
            }
            if (RELU) {
                v0 = fmaxf(v0, 0.f); v1 = fmaxf(v1, 0.f);
                v2 = fmaxf(v2, 0.f); v3 = fmaxf(v3, 0.f);
            }
            size_t idx = (size_t)row * N + nb;
            uint2 ov;
            ov.x = (u32)f2b(v0) | ((u32)f2b(v1) << 16);
            ov.y = (u32)f2b(v2) | ((u32)f2b(v3) << 16);
            *(uint2*)&out[idx] = ov;
        }
    }
}

// ---------------- tail_fused: proj + LN2 + FFN, one kernel ------------------
__global__ __launch_bounds__(512, 1) void tail_fused(const u16* __restrict__ att,
                                                     const u16* __restrict__ wpT,
                                                     const float* __restrict__ bp,
                                                     const float* __restrict__ x,
                                                     const float* __restrict__ g2,
                                                     const float* __restrict__ be2,
                                                     const u16* __restrict__ w1T,
                                                     const float* __restrict__ b1,
                                                     const u16* __restrict__ w2T,
                                                     const float* __restrict__ b2,
                                                     float* __restrict__ out) {
    __shared__ __align__(16) u16 SH[65536];   // 128KB: Ms/Hs 32K | Bs 3x32K
    __shared__ float ps[2][2][16][4], pq[2][2][16][4];
    u16* Ms = SH;             // [4 kc][64][64]: h2 (interlude) then mid chunks
    u16* Bs = SH + 16384;     // 3 x [256][64] weight tile (triple buffer)
    const int tid = threadIdx.x, lane = tid & 63, w = tid >> 6;
    const int m0 = blockIdx.x * 64;
    const int wmi = w & 1, wni = w >> 1;
    const int wm = wmi * 32;                  // m-half (32 rows)
    const int wn = wni * 64;                  // n-quarter (64 cols)
    const int fm = lane & 15, q = lane >> 4;
    const int sw = fm & 7;
    const int kset = ((lane & 7) ^ (lane >> 3)) * 8;
    const int rb = w * 8 + (lane >> 3);       // staging row 0..63

    // ---- A-frags (att) into registers: ar[kcn][mi] = att[row][kcn*32+q*8] --
    short8v ar[8][2];
    {
        const u16* Abase = att + (size_t)(m0 + wm + fm) * 256 + q * 8;
        #pragma unroll
        for (int kcn = 0; kcn < 8; kcn++)
            #pragma unroll
            for (int mi = 0; mi < 2; mi++)
                ar[kcn][mi] = *(const short8v*)(Abase + (size_t)mi * 16 * 256 + kcn * 32);
    }

    // ---- B-tile issue: u<4 -> wpT chunk u; u>=4 -> ffn tile u-4 ----
    auto issueB = [&](int u, u16* dst) {
        if (u < 4) {
            const u16* src = wpT + (size_t)rb * 256 + u * 64 + kset;
            #pragma unroll
            for (int c = 0; c < 4; c++)
                async_cp16(src + (size_t)c * 64 * 256, dst + c * 4096);
        } else {
            const int tt = u - 4, n2 = tt >> 3, k2 = tt & 3;
            if (((tt >> 2) & 1) == 0) {
                const u16* src = w1T + (size_t)(n2 * 256 + rb) * 256 + k2 * 64 + kset;
                #pragma unroll
                for (int c = 0; c < 4; c++)
                    async_cp16(src + (size_t)c * 64 * 256, dst + c * 4096);
            } else {
                const u16* src = w2T + (size_t)rb * 1024 + n2 * 256 + k2 * 64 + kset;
                #pragma unroll
                for (int c = 0; c < 4; c++)
                    async_cp16(src + (size_t)c * 64 * 1024, dst + c * 4096);
            }
        }
    };

    issueB(0, Bs + w * 512);
    issueB(1, Bs + 16384 + w * 512);

    float4v acc1[2][4], acc2[2][4], xr[2][4];
    #pragma unroll
    for (int i = 0; i < 2; i++)
        #pragma unroll
        for (int j = 0; j < 4; j++) {
            acc1[i][j] = (float4v){0.f, 0.f, 0.f, 0.f};   // proj accumulator
            acc2[i][j] = (float4v){0.f, 0.f, 0.f, 0.f};
        }

    #pragma unroll
    for (int t = 0; t < 36; ++t) {
        if (t == 35) asm volatile("s_waitcnt vmcnt(0)" ::: "memory");
        else         asm volatile("s_waitcnt vmcnt(4)" ::: "memory");
        __builtin_amdgcn_s_barrier();
        if (t + 2 < 36)
            issueB(t + 2, Bs + ((t + 2) % 3) * 16384 + w * 512);
        const u16* Bb = Bs + (t % 3) * 16384;

        if (t < 4) {
            // ---- proj tile t: acc1 += att-frag x wpT-tile ----
            __builtin_amdgcn_s_setprio(1);
            #pragma unroll
            for (int kk = 0; kk < 64; kk += 32) {
                const int slot = (((kk >> 3) + q) ^ sw) * 8;
                short8v bf[4];
                #pragma unroll
                for (int ni = 0; ni < 4; ni++)
                    bf[ni] = *(const short8v*)&Bb[(wn + ni * 16 + fm) * 64 + slot];
                #pragma unroll
                for (int mi = 0; mi < 2; mi++)
                    #pragma unroll
                    for (int ni = 0; ni < 4; ni++)
                        acc1[mi][ni] = __builtin_amdgcn_mfma_f32_16x16x32_bf16(
                            bf[ni], ar[t * 2 + (kk >> 5)][mi], acc1[mi][ni], 0, 0, 0);
            }
            __builtin_amdgcn_s_setprio(0);
            if (t == 3) {
                // ======== LN2 interlude ========
                float s[2] = {0.f, 0.f}, s2[2] = {0.f, 0.f};
                #pragma unroll
                for (int mi = 0; mi < 2; mi++)
                    #pragma unroll
                    for (int ni = 0; ni < 4; ni++) {
                        const int nb = wn + ni * 16 + q * 4;
                        const int row = m0 + wm + mi * 16 + fm;
                        float4 bv = *(const float4*)&bp[nb];
                        float4 xv = *(const float4*)(x + (size_t)row * 256 + nb);
                        #pragma unroll
                        for (int r = 0; r < 4; r++) {
                            float tv = acc1[mi][ni][r] + (&bv.x)[r] + (&xv.x)[r];
                            xr[mi][ni][r] = tv;
                            s[mi] += tv; s2[mi] += tv * tv;
                        }
                    }
                #pragma unroll
                for (int mi = 0; mi < 2; mi++) {
                    s[mi]  += __shfl_xor(s[mi], 16);  s[mi]  += __shfl_xor(s[mi], 32);
                    s2[mi] += __shfl_xor(s2[mi], 16); s2[mi] += __shfl_xor(s2[mi], 32);
                }
                if (q == 0) {
                    ps[wmi][0][fm][wni] = s[0];  ps[wmi][1][fm][wni] = s[1];
                    pq[wmi][0][fm][wni] = s2[0]; pq[wmi][1][fm][wni] = s2[1];
                }
                asm volatile("s_waitcnt lgkmcnt(0)" ::: "memory");
                __builtin_amdgcn_s_barrier();
                float mu[2], rs[2];
                #pragma unroll
                for (int mi = 0; mi < 2; mi++) {
                    float S  = ps[wmi][mi][fm][0] + ps[wmi][mi][fm][1]
                             + ps[wmi][mi][fm][2] + ps[wmi][mi][fm][3];
                    float SQ = pq[wmi][mi][fm][0] + pq[wmi][mi][fm][1]
                             + pq[wmi][mi][fm][2] + pq[wmi][mi][fm][3];
                    mu[mi] = S * 0.00390625f;
                    rs[mi] = rsqrtf(SQ * 0.00390625f - mu[mi] * mu[mi] + 1e-5f);
                }
                // h2 -> Ms (Hs) in swizzled A layout
                #pragma unroll
                for (int ni = 0; ni < 4; ni++) {
                    const int c2 = wn + ni * 16 + q * 4;
                    const int kcM = c2 >> 6, cc = c2 & 63;
                    float4 gv = *(const float4*)&g2[c2];
                    float4 bv = *(const float4*)&be2[c2];
                    #pragma unroll
                    for (int mi = 0; mi < 2; mi++) {
                        const int row = wm + mi * 16 + fm;
                        float h0 = (xr[mi][ni][0] - mu[mi]) * rs[mi] * gv.x + bv.x;
                        float h1 = (xr[mi][ni][1] - mu[mi]) * rs[mi] * gv.y + bv.y;
                        float h2v = (xr[mi][ni][2] - mu[mi]) * rs[mi] * gv.z + bv.z;
                        float h3 = (xr[mi][ni][3] - mu[mi]) * rs[mi] * gv.w + bv.w;
                        uint2 pp;
                        pp.x = (u32)f2b(h0) | ((u32)f2b(h1) << 16);
                        pp.y = (u32)f2b(h2v) | ((u32)f2b(h3) << 16);
                        *(uint2*)&Ms[kcM * 4096 + row * 64 +
                                     (((cc >> 3) ^ (row & 7)) * 8) + (cc & 7)] = pp;
                    }
                }
                asm volatile("s_waitcnt lgkmcnt(0)" ::: "memory");
                __builtin_amdgcn_s_barrier();
                // reload ar from Ms(Hs): ar[kcn][mi] = h2[row][kcn*32 + q*8]
                #pragma unroll
                for (int kcn = 0; kcn < 8; kcn++) {
                    const int kcq = kcn >> 1, kk = (kcn & 1) * 32;
                    const int slot = (((kk >> 3) + q) ^ sw) * 8;
                    #pragma unroll
                    for (int mi = 0; mi < 2; mi++)
                        ar[kcn][mi] = *(const short8v*)&Ms[kcq * 4096 +
                                        (wm + mi * 16 + fm) * 64 + slot];
                }
            }
        } else {
            const int tt = t - 4;
            const int nch = tt >> 3, ph = (tt >> 2) & 1, kc = tt & 3;
            if (ph == 0) {
                if (kc == 0) {
                    #pragma unroll
                    for (int i = 0; i < 2; i++)
                        #pragma unroll
                        for (int j = 0; j < 4; j++) acc1[i][j] = (float4v){0.f, 0.f, 0.f, 0.f};
                }
                __builtin_amdgcn_s_setprio(1);
                #pragma unroll
                for (int kk = 0; kk < 64; kk += 32) {
                    const int slot = (((kk >> 3) + q) ^ sw) * 8;
                    short8v bf[4];
                    #pragma unroll
                    for (int ni = 0; ni < 4; ni++)
                        bf[ni] = *(const short8v*)&Bb[(wn + ni * 16 + fm) * 64 + slot];
                    #pragma unroll
                    for (int mi = 0; mi < 2; mi++)
                        #pragma unroll
                        for (int ni = 0; ni < 4; ni++)
                            acc1[mi][ni] = __builtin_amdgcn_mfma_f32_16x16x32_bf16(
                                bf[ni], ar[kc * 2 + (kk >> 5)][mi], acc1[mi][ni], 0, 0, 0);
                }
                __builtin_amdgcn_s_setprio(0);
                if (kc == 3) {
                    // bias + relu -> Ms (swizzled A layout for gemm2)
                    #pragma unroll
                    for (int ni = 0; ni < 4; ni++) {
                        const int c2 = wn + ni * 16 + q * 4;       // 0..255
                        const int kcM = c2 >> 6, cc = c2 & 63;
                        float4 bv = *(const float4*)&b1[nch * 256 + c2];
                        #pragma unroll
                        for (int mi = 0; mi < 2; mi++) {
                            const int row = wm + mi * 16 + fm;
                            float v0 = fmaxf(acc1[mi][ni][0] + bv.x, 0.f);
                            float v1 = fmaxf(acc1[mi][ni][1] + bv.y, 0.f);
                            float v2 = fmaxf(acc1[mi][ni][2] + bv.z, 0.f);
                            float v3 = fmaxf(acc1[mi][ni][3] + bv.w, 0.f);
                            uint2 pp;
                            pp.x = (u32)f2b(v0) | ((u32)f2b(v1) << 16);
                            pp.y = (u32)f2b(v2) | ((u32)f2b(v3) << 16);
                            *(uint2*)&Ms[kcM * 4096 + row * 64 +
                                         (((cc >> 3) ^ (row & 7)) * 8) + (cc & 7)] = pp;
                        }
                    }
                    asm volatile("s_waitcnt lgkmcnt(0)" ::: "memory");
                }
            } else {
                const u16* Ab = Ms + kc * 4096;
                __builtin_amdgcn_s_setprio(1);
                #pragma unroll
                for (int kk = 0; kk < 64; kk += 32) {
                    const int slot = (((kk >> 3) + q) ^ sw) * 8;
                    short8v af[2], bf[4];
                    #pragma unroll
                    for (int mi = 0; mi < 2; mi++)
                        af[mi] = *(const short8v*)&Ab[(wm + mi * 16 + fm) * 64 + slot];
                    #pragma unroll
                    for (int ni = 0; ni < 4; ni++)
                        bf[ni] = *(const short8v*)&Bb[(wn + ni * 16 + fm) * 64 + slot];
                    #pragma unroll
                    for (int mi = 0; mi < 2; mi++)
                        #pragma unroll
                        for (int ni = 0; ni < 4; ni++)
                            acc2[mi][ni] = __builtin_amdgcn_mfma_f32_16x16x32_bf16(
                                bf[ni], af[mi], acc2[mi][ni], 0, 0, 0);
                }
                __builtin_amdgcn_s_setprio(0);
            }
        }
    }

    // ---- epilogue: out = xr (= x + att@wp + bp) + acc2 + b2, fp32 stores ---
    #pragma unroll
    for (int mi = 0; mi < 2; mi++) {
        const int row = m0 + wm + mi * 16 + fm;
        #pragma unroll
        for (int ni = 0; ni < 4; ni++) {
            const int nb = wn + ni * 16 + q * 4;
            size_t idx = (size_t)row * 256 + nb;
            float4 bv = *(const float4*)&b2[nb];
            float v0 = acc2[mi][ni][0] + bv.x + xr[mi][ni][0];
            float v1 = acc2[mi][ni][1] + bv.y + xr[mi][ni][1];
            float v2 = acc2[mi][ni][2] + bv.z + xr[mi][ni][2];
            float v3 = acc2[mi][ni][3] + bv.w + xr[mi][ni][3];
            *(float4*)&out[idx] = (float4){v0, v1, v2, v3};
        }
    }
}

// ---------------- MFMA flash attention: dbuf K/V, 1 barrier/tile ------------
__global__ __launch_bounds__(256) void attn_mfma(const u16* __restrict__ qk,
                                                 const u16* __restrict__ vtg,
                                                 u16* __restrict__ att) {
    const int T = 1024;
    int jj = (blockIdx.x + (blockIdx.y >> 3)) & 7;
    int b = blockIdx.y >> 3, hh = blockIdx.y & 7;
    int tid = threadIdx.x;
    int lane = tid & 63, w = tid >> 6;
    int fm = lane & 15, q = lane >> 4;

    __shared__ __align__(16) u16 Ks[2][64][72];
    __shared__ __align__(16) u16 Vt[2][32][72];
    __shared__ __align__(16) u16 Pl[4][16][72];

    size_t base = (size_t)b * T * 512;
    const u16* kb = qk + base + 256 + hh * 32;
    const u16* vt = vtg + (size_t)((b * 8 + hh) * 32) * 1024;
    const int krow = tid >> 2, kcol = (tid & 3) * 8;
    const int vd = tid >> 3, vs = (tid & 7) * 8;

    int qa0 = jj * 64, qb0 = (15 - jj) * 64;
    int tqa = qa0 + w * 16 + fm, tqb = qb0 + w * 16 + fm;
    short8v qfa = *(const short8v*)(qk + base + (size_t)tqa * 512 + hh * 32 + q * 8);
    short8v qfb = *(const short8v*)(qk + base + (size_t)tqb * 512 + hh * 32 + q * 8);
    float4v oa0 = {0.f, 0.f, 0.f, 0.f}, oa1 = {0.f, 0.f, 0.f, 0.f};
    float4v ob0 = {0.f, 0.f, 0.f, 0.f}, ob1 = {0.f, 0.f, 0.f, 0.f};
    float la = 0.f, lb = 0.f;
    int wqa = qa0 + w * 16, wqb = qb0 + w * 16;
    int nIter = 16 - jj;

    uint4 kreg = *(const uint4*)(kb + (size_t)krow * 512 + kcol);
    uint4 vreg = *(const uint4*)(vt + (size_t)vd * 1024 + vs);

    for (int it = 0; it < nIter; ++it) {
        int s0 = it << 6;
        const int cb = it & 1;
        // write tile it into buf cb (reads of cb ended 2 barriers ago),
        // prefetch tile it+1 into regs, ONE barrier, read frags from cb.
        *(uint4*)&Ks[cb][krow][kcol] = kreg;
        *(uint4*)&Vt[cb][vd][vs] = vreg;
        if (it + 1 < nIter) {
            int ns0 = s0 + 64;
            kreg = *(const uint4*)(kb + (size_t)(ns0 + krow) * 512 + kcol);
            vreg = *(const uint4*)(vt + (size_t)vd * 1024 + ns0 + vs);
        }
        asm volatile("s_waitcnt lgkmcnt(0)" ::: "memory");
        __builtin_amdgcn_s_barrier();
        short8v kf0 = *(const short8v*)&Ks[cb][fm][q * 8];
        short8v kf1 = *(const short8v*)&Ks[cb][16 + fm][q * 8];
        short8v kf2 = *(const short8v*)&Ks[cb][32 + fm][q * 8];
        short8v kf3 = *(const short8v*)&Ks[cb][48 + fm][q * 8];
        short8v vf00 = *(const short8v*)&Vt[cb][fm][q * 8];
        short8v vf01 = *(const short8v*)&Vt[cb][fm][32 + q * 8];
        short8v vf10 = *(const short8v*)&Vt[cb][16 + fm][q * 8];
        short8v vf11 = *(const short8v*)&Vt[cb][16 + fm][32 + q * 8];
        float4v z = {0.f, 0.f, 0.f, 0.f};

        #pragma unroll
        for (int t2 = 0; t2 < 2; t2++) {       // t2=0: tile b (large), 1: tile a
            int wq0 = t2 ? wqa : wqb;
            if (s0 >= wq0 + 16) continue;      // wave-uniform causal skip
            int tq = t2 ? tqa : tqb;
            short8v qf = t2 ? qfa : qfb;
            __builtin_amdgcn_s_setprio(1);
            float4v s_0 = __builtin_amdgcn_mfma_f32_16x16x32_bf16(kf0, qf, z, 0, 0, 0);
            float4v s_1 = __builtin_amdgcn_mfma_f32_16x16x32_bf16(kf1, qf, z, 0, 0, 0);
            float4v s_2 = __builtin_amdgcn_mfma_f32_16x16x32_bf16(kf2, qf, z, 0, 0, 0);
            float4v s_3 = __builtin_amdgcn_mfma_f32_16x16x32_bf16(kf3, qf, z, 0, 0, 0);
            __builtin_amdgcn_s_setprio(0);
            float p[16];
            #pragma unroll
            for (int r = 0; r < 4; r++) {
                p[r] = exp2f(s_0[r]); p[4 + r] = exp2f(s_1[r]);
                p[8 + r] = exp2f(s_2[r]); p[12 + r] = exp2f(s_3[r]);
            }
            if (s0 + 63 > wq0) {               // diagonal region: causal mask
                int sb = s0 + q * 4;
                #pragma unroll
                for (int c = 0; c < 4; c++)
                    #pragma unroll
                    for (int r = 0; r < 4; r++)
                        if (sb + c * 16 + r > tq) p[c * 4 + r] = 0.f;
            }
            float rsum = 0.f;
            #pragma unroll
            for (int i = 0; i < 16; i++) rsum += p[i];
            rsum += __shfl_xor(rsum, 16);
            rsum += __shfl_xor(rsum, 32);
            if (t2) la += rsum; else lb += rsum;

            #pragma unroll
            for (int c = 0; c < 4; c++) {
                uint2 pp;
                pp.x = pk2_rtz(p[c * 4 + 0], p[c * 4 + 1]);
                pp.y = pk2_rtz(p[c * 4 + 2], p[c * 4 + 3]);
                *(uint2*)&Pl[w][fm][c * 16 + q * 4] = pp;   // wave-internal
            }
            short8v pf0 = *(const short8v*)&Pl[w][fm][q * 8];
            short8v pf1 = *(const short8v*)&Pl[w][fm][32 + q * 8];
            __builtin_amdgcn_s_setprio(1);
            if (t2) {
                oa0 = __builtin_amdgcn_mfma_f32_16x16x32_bf16(vf00, pf0, oa0, 0, 0, 0);
                oa0 = __builtin_amdgcn_mfma_f32_16x16x32_bf16(vf01, pf1, oa0, 0, 0, 0);
                oa1 = __builtin_amdgcn_mfma_f32_16x16x32_bf16(vf10, pf0, oa1, 0, 0, 0);
                oa1 = __builtin_amdgcn_mfma_f32_16x16x32_bf16(vf11, pf1, oa1, 0, 0, 0);
            } else {
                ob0 = __builtin_amdgcn_mfma_f32_16x16x32_bf16(vf00, pf0, ob0, 0, 0, 0);
                ob0 = __builtin_amdgcn_mfma_f32_16x16x32_bf16(vf01, pf1, ob0, 0, 0, 0);
                ob1 = __builtin_amdgcn_mfma_f32_16x16x32_bf16(vf10, pf0, ob1, 0, 0, 0);
                ob1 = __builtin_amdgcn_mfma_f32_16x16x32_bf16(vf11, pf1, ob1, 0, 0, 0);
            }
            __builtin_amdgcn_s_setprio(0);
        }
    }

    #pragma unroll
    for (int t2 = 0; t2 < 2; t2++) {
        float inv = 1.f / (t2 ? la : lb);
        float4v o0 = t2 ? oa0 : ob0, o1 = t2 ? oa1 : ob1;
        int tq = t2 ? tqa : tqb;
        uint2 r0, r1;
        r0.x = (u32)f2b(o0[0] * inv) | ((u32)f2b(o0[1] * inv) << 16);
        r0.y = (u32)f2b(o0[2] * inv) | ((u32)f2b(o0[3] * inv) << 16);
        r1.x = (u32)f2b(o1[0] * inv) | ((u32)f2b(o1[1] * inv) << 16);
        r1.y = (u32)f2b(o1[2] * inv) | ((u32)f2b(o1[3] * inv) << 16);
        size_t o = (size_t)(b * T + tq) * 256 + hh * 32;
        *(uint2*)(att + o + q * 4) = r0;
        *(uint2*)(att + o + 16 + q * 4) = r1;
    }
}

// ---------------- launch ----------------
extern "C" void kernel_launch(void* const* d_in, const int* in_sizes, int n_in,
                              void* d_out, int out_size, void* d_ws, size_t ws_size,
                              hipStream_t stream) {
    const int BT = 16 * 1024;
    const float* x      = (const float*)d_in[0];
    const float* wq     = (const float*)d_in[1];
    const float* wk     = (const float*)d_in[2];
    const float* wv     = (const float*)d_in[3];
    const float* w_proj = (const float*)d_in[4];
    const float* b_proj = (const float*)d_in[5];
    const float* w1     = (const float*)d_in[6];
    const float* b1     = (const float*)d_in[7];
    const float* w2     = (const float*)d_in[8];
    const float* b2     = (const float*)d_in[9];
    const float* ln1_g  = (const float*)d_in[10];
    const float* ln1_b  = (const float*)d_in[11];
    const float* ln2_g  = (const float*)d_in[12];
    const float* ln2_b  = (const float*)d_in[13];

    // Workspace: [8M,16M) hbuf h->att | [16M,32M) qk | [32M,48M) vtg
    //            [48M...) packed weights (1.5M)
    char* ws = (char*)d_ws;
    const size_t MB = 1024 * 1024;
    u16*  hbuf  = (u16*)(ws + 8 * MB);
    u16*  qk    = (u16*)(ws + 16 * MB);
    u16*  vtg   = (u16*)(ws + 32 * MB);
    u16*  wqkvT = (u16*)(ws + 48 * MB);
    u16*  wpT   = (u16*)(ws + 48 * MB + 0x60000);
    u16*  w1T   = (u16*)(ws + 48 * MB + 0x80000);
    u16*  w2T   = (u16*)(ws + 48 * MB + 0x100000);

    prep_ln1<<<5008, 256, 0, stream>>>(wq, wk, wv, w_proj, w1, w2, x, ln1_g, ln1_b,
                                       wqkvT, wpT, w1T, w2T, hbuf);
    // qk | vtg = h @ [Wq'|Wk|Wv]  [counted-vmcnt dbuf]
    gemm128<false, false, true><<<dim3(128, 6), 256, 0, stream>>>(
        hbuf, wqkvT, nullptr, qk, vtg, BT, 512, 256);
    // att = flash attention (writes over h)  [dbuf K/V, 1 barrier/tile]
    attn_mfma<<<dim3(8, 128), 256, 0, stream>>>(qk, vtg, hbuf);
    // out = x2 + relu(LN2(x + att@wp + bp) @ w1 + b1) @ w2 + b2  [one kernel]
    tail_fused<<<256, 512, 0, stream>>>(hbuf, wpT, b_proj, x, ln2_g, ln2_b,
                                        w1T, b1, w2T, b2, (float*)d_out);
}